// Round 1
// baseline (701.507 us; speedup 1.0000x reference)
//
#include <hip/hip_runtime.h>
#include <hip/hip_bf16.h>
#include <stdint.h>

#define N_DIM 2048
#define BATCH_SZ 8192

typedef __bf16 bf16;
typedef __bf16 bf16x4 __attribute__((ext_vector_type(4)));
typedef __bf16 bf16x8 __attribute__((ext_vector_type(8)));
typedef float f32x4 __attribute__((ext_vector_type(4)));

// Build Sb = bf16(S), SbT = bf16(S') where S' = -S = S^T, and Qf = I + S' (fp32).
// We compute Q^T = exp(S') so the final GEMM's Bt operand needs no transpose.
__global__ void unfold_kernel(const float* __restrict__ Sflat,
                              bf16* __restrict__ Sb,
                              bf16* __restrict__ SbT,
                              float* __restrict__ Qf) {
  int idx = blockIdx.x * blockDim.x + threadIdx.x;
  int i = idx >> 11;            // row (N_DIM = 2048)
  int j = idx & (N_DIM - 1);    // col
  float v = 0.0f;               // v = S[i][j]
  if (i < j) {
    int fi = i * (N_DIM - 1) - ((i * (i - 1)) >> 1) + (j - i - 1);
    v = Sflat[fi];
  } else if (i > j) {
    int fi = j * (N_DIM - 1) - ((j * (j - 1)) >> 1) + (i - j - 1);
    v = -Sflat[fi];
  }
  Sb[idx]  = (bf16)v;
  SbT[idx] = (bf16)(-v);
  Qf[idx]  = (i == j ? 1.0f : 0.0f) - v;
}

// fp32 -> bf16 elementwise (vectorized x4)
__global__ void cast_kernel(const float* __restrict__ in, bf16* __restrict__ out) {
  int t = blockIdx.x * blockDim.x + threadIdx.x;
  float4 v = ((const float4*)in)[t];
  bf16x4 o;
  o.x = (bf16)v.x; o.y = (bf16)v.y; o.z = (bf16)v.z; o.w = (bf16)v.w;
  ((bf16x4*)out)[t] = o;
}

// C(MxN) = alpha * A(MxK) @ Bt(NxK)^T, bf16 inputs, fp32 accumulate.
// TAYLOR=1: Qf += val; Tout = bf16(val)   (Taylor-term recurrence step)
// TAYLOR=0: C = val                        (final output write)
// 128x128 block tile, BK=32, 4 waves each computing a 64x64 sub-tile.
template <int TAYLOR>
__global__ __launch_bounds__(256) void gemm_bt(
    const bf16* __restrict__ A, const bf16* __restrict__ Bt,
    float* __restrict__ C, bf16* __restrict__ Tout, float alpha,
    int M, int N, int K) {
  __shared__ __align__(16) bf16 As[128 * 32];
  __shared__ __align__(16) bf16 Bs[128 * 32];

  const int tid  = threadIdx.x;
  const int lane = tid & 63;
  const int wave = tid >> 6;
  const int wr   = wave >> 1;   // wave row (0..1)
  const int wc   = wave & 1;    // wave col (0..1)
  const int quad = lane >> 4;   // 0..3
  const int l16  = lane & 15;
  const int m0 = blockIdx.y * 128;
  const int n0 = blockIdx.x * 128;

  f32x4 acc[4][4] = {};

  // Staging: 512 x 16B segments; each thread does 2 (A) + 2 (B).
  const int r0 = tid >> 2;          // 0..63
  const int r1 = r0 + 64;           // 64..127
  const int c0 = (tid & 3) * 8;     // bf16 element offset within 32-wide row

  for (int k0 = 0; k0 < K; k0 += 32) {
    __syncthreads();
    *(uint4*)&As[r0 * 32 + c0] = *(const uint4*)&A [(size_t)(m0 + r0) * K + k0 + c0];
    *(uint4*)&As[r1 * 32 + c0] = *(const uint4*)&A [(size_t)(m0 + r1) * K + k0 + c0];
    *(uint4*)&Bs[r0 * 32 + c0] = *(const uint4*)&Bt[(size_t)(n0 + r0) * K + k0 + c0];
    *(uint4*)&Bs[r1 * 32 + c0] = *(const uint4*)&Bt[(size_t)(n0 + r1) * K + k0 + c0];
    __syncthreads();

    bf16x8 af[4], bfr[4];
#pragma unroll
    for (int mi = 0; mi < 4; ++mi)
      af[mi] = *(const bf16x8*)&As[(wr * 64 + mi * 16 + l16) * 32 + quad * 8];
#pragma unroll
    for (int ni = 0; ni < 4; ++ni)
      bfr[ni] = *(const bf16x8*)&Bs[(wc * 64 + ni * 16 + l16) * 32 + quad * 8];
#pragma unroll
    for (int mi = 0; mi < 4; ++mi)
#pragma unroll
      for (int ni = 0; ni < 4; ++ni)
        acc[mi][ni] = __builtin_amdgcn_mfma_f32_16x16x32_bf16(
            af[mi], bfr[ni], acc[mi][ni], 0, 0, 0);
  }

  // Epilogue. C/D layout: col = lane&15, row = quad*4 + reg.
#pragma unroll
  for (int mi = 0; mi < 4; ++mi) {
    const int rbase = m0 + wr * 64 + mi * 16 + quad * 4;
#pragma unroll
    for (int ni = 0; ni < 4; ++ni) {
      const int col = n0 + wc * 64 + ni * 16 + l16;
#pragma unroll
      for (int r = 0; r < 4; ++r) {
        size_t idx = (size_t)(rbase + r) * N + col;
        float val = acc[mi][ni][r] * alpha;
        if (TAYLOR) {
          C[idx] += val;          // Qf accumulation (unique ownership, no race)
          Tout[idx] = (bf16)val;  // next Taylor term input
        } else {
          C[idx] = val;
        }
      }
    }
  }
}

extern "C" void kernel_launch(void* const* d_in, const int* in_sizes, int n_in,
                              void* d_out, int out_size, void* d_ws, size_t ws_size,
                              hipStream_t stream) {
  const float* X     = (const float*)d_in[0];
  const float* Sflat = (const float*)d_in[1];
  float* out = (float*)d_out;
  char* ws = (char*)d_ws;

  // Workspace layout (80 MB total):
  bf16*  Xb  = (bf16*)(ws);                  // 32 MB  bf16(X)
  float* Qf  = (float*)(ws + (32u << 20));   // 16 MB  Q^T accumulator (fp32)
  bf16*  Sb  = (bf16*)(ws + (48u << 20));    //  8 MB  bf16(S)   = Bt for Taylor GEMMs
  bf16*  SbT = (bf16*)(ws + (56u << 20));    //  8 MB  bf16(-S)  = T'_1; reused as Qtb later
  bf16*  Ta  = (bf16*)(ws + (64u << 20));    //  8 MB  Taylor term ping
  bf16*  Tb2 = (bf16*)(ws + (72u << 20));    //  8 MB  Taylor term pong
  bf16*  Qtb = SbT;  // SbT is dead after the i=2 GEMM; reuse for bf16(Q^T)

  unfold_kernel<<<(N_DIM * N_DIM) / 256, 256, 0, stream>>>(Sflat, Sb, SbT, Qf);
  cast_kernel<<<(BATCH_SZ * N_DIM / 4) / 256, 256, 0, stream>>>(X, Xb);

  // Taylor chain on S' = -S:  T'_i = T'_{i-1} @ S' / i;  Qf += T'_i.
  // GEMM computes A @ Sb^T = A @ S', since Sb^T = S^T = -S = S'.
  const bf16* Ain = SbT;
  bf16* bufs[2] = {Ta, Tb2};
  for (int i = 2; i <= 9; ++i) {
    bf16* Tout = bufs[i & 1];
    gemm_bt<1><<<dim3(N_DIM / 128, N_DIM / 128), 256, 0, stream>>>(
        Ain, Sb, Qf, Tout, 1.0f / (float)i, N_DIM, N_DIM, N_DIM);
    Ain = Tout;
  }

  // Qtb = bf16(Qf) — this IS row-major Q^T, i.e. the Bt operand of out = X @ Q.
  cast_kernel<<<(N_DIM * N_DIM / 4) / 256, 256, 0, stream>>>(Qf, Qtb);

  gemm_bt<0><<<dim3(N_DIM / 128, BATCH_SZ / 128), 256, 0, stream>>>(
      Xb, Qtb, out, nullptr, 1.0f, BATCH_SZ, N_DIM, N_DIM);
}

// Round 2
// 415.173 us; speedup vs baseline: 1.6897x; 1.6897x over previous
//
#include <hip/hip_runtime.h>
#include <hip/hip_bf16.h>
#include <stdint.h>

#define N_DIM 2048
#define BATCH_SZ 8192

typedef __bf16 bf16;
typedef __bf16 bf16x4 __attribute__((ext_vector_type(4)));
typedef __bf16 bf16x8 __attribute__((ext_vector_type(8)));
typedef float f32x4 __attribute__((ext_vector_type(4)));

// Taylor coefficients 1/i!
#define C3 (1.0f/6.0f)
#define C4 (1.0f/24.0f)
#define C5 (1.0f/120.0f)
#define C6 (1.0f/720.0f)
#define C7 (1.0f/5040.0f)
#define C8 (1.0f/40320.0f)
#define C9 (1.0f/362880.0f)

// Async global->LDS, 16B per lane. LDS dest is wave-uniform base + lane*16.
__device__ __forceinline__ void gld16(const bf16* g, bf16* l) {
  __builtin_amdgcn_global_load_lds(
      (const __attribute__((address_space(1))) void*)g,
      (__attribute__((address_space(3))) void*)l, 16, 0, 0);
}

// Build Wb = bf16(W) where W = -S (so exp(W) = Q^T), Wtb = bf16(W^T) = bf16(S).
__global__ void unfold_kernel(const float* __restrict__ Sflat,
                              bf16* __restrict__ Wb,
                              bf16* __restrict__ Wtb) {
  int idx = blockIdx.x * blockDim.x + threadIdx.x;
  int i = idx >> 11;            // row
  int j = idx & (N_DIM - 1);    // col
  float v = 0.0f;               // v = S[i][j]
  if (i < j) {
    int fi = i * (N_DIM - 1) - ((i * (i - 1)) >> 1) + (j - i - 1);
    v = Sflat[fi];
  } else if (i > j) {
    int fi = j * (N_DIM - 1) - ((j * (j - 1)) >> 1) + (i - j - 1);
    v = -Sflat[fi];
  }
  Wb[idx]  = (bf16)(-v);   // W = -S
  Wtb[idx] = (bf16)(v);    // W^T = S
}

// fp32 -> bf16 elementwise (vectorized x4)
__global__ void cast_kernel(const float* __restrict__ in, bf16* __restrict__ out) {
  int t = blockIdx.x * blockDim.x + threadIdx.x;
  float4 v = ((const float4*)in)[t];
  bf16x4 o;
  o.x = (bf16)v.x; o.y = (bf16)v.y; o.z = (bf16)v.z; o.w = (bf16)v.w;
  ((bf16x4*)out)[t] = o;
}

// C(MxN) = A(MxK) @ Bt(NxK)^T, bf16 in, fp32 accumulate.
// 128x128 tile, BK=32, 4 waves x (64x64), global_load_lds width-16 staging.
// MODE 0: Cf[idx] = acc                                  (final output)
// MODE 1: O1 = bf16(acc)                                 (W2 = W@W)
// MODE 2: O1 = bf16(-acc)  [W3^T],  O2 = bf16(P2)        (W3 = W2@W)
//         P2 = C6*I + C7*W + C8*W2 + C9*W3
// MODE 3: O1 = bf16(acc + C3*I + C4*W + C5*W2)           (P1 = B1 + P2@W3)
// MODE 4: O1 = bf16(acc +    I +    W + 0.5*W2)          (Q^T = B0 + P1@W3)
template <int MODE>
__global__ __launch_bounds__(256) void gemm_bt(
    const bf16* __restrict__ A, const bf16* __restrict__ Bt,
    float* __restrict__ Cf, bf16* __restrict__ O1, bf16* __restrict__ O2,
    const bf16* __restrict__ Wb, const bf16* __restrict__ W2b,
    int M, int N, int K) {
  __shared__ __align__(16) bf16 As[128 * 32];
  __shared__ __align__(16) bf16 Bs[128 * 32];

  const int tid  = threadIdx.x;
  const int lane = tid & 63;
  const int wave = tid >> 6;
  const int wr   = wave >> 1;
  const int wc   = wave & 1;
  const int quad = lane >> 4;
  const int l16  = lane & 15;
  const int m0 = blockIdx.y * 128;
  const int n0 = blockIdx.x * 128;

  // Staging: wave w stages rows [w*16, w*16+16) and [64+w*16, ...) of both tiles.
  // Lane i -> row (i>>2) within chunk, byte col (i&3)*16; LDS dest base+lane*16.
  const int srow = wave * 16 + (lane >> 2);
  const int scol = (lane & 3) * 8;
  const bf16* gA0 = A  + (size_t)(m0 + srow) * K + scol;
  const bf16* gA1 = A  + (size_t)(m0 + 64 + srow) * K + scol;
  const bf16* gB0 = Bt + (size_t)(n0 + srow) * K + scol;
  const bf16* gB1 = Bt + (size_t)(n0 + 64 + srow) * K + scol;
  bf16* lA0 = As + (wave * 16) * 32;       // wave-uniform LDS bases
  bf16* lA1 = As + (64 + wave * 16) * 32;
  bf16* lB0 = Bs + (wave * 16) * 32;
  bf16* lB1 = Bs + (64 + wave * 16) * 32;

  f32x4 acc[4][4] = {};

  for (int k0 = 0; k0 < K; k0 += 32) {
    __syncthreads();                       // previous consumers done with LDS
    gld16(gA0, lA0);
    gld16(gA1, lA1);
    gld16(gB0, lB0);
    gld16(gB1, lB1);
    gA0 += 32; gA1 += 32; gB0 += 32; gB1 += 32;
    __syncthreads();                       // drains vmcnt -> LDS valid

    bf16x8 af[4], bfr[4];
#pragma unroll
    for (int mi = 0; mi < 4; ++mi)
      af[mi] = *(const bf16x8*)&As[(wr * 64 + mi * 16 + l16) * 32 + quad * 8];
#pragma unroll
    for (int ni = 0; ni < 4; ++ni)
      bfr[ni] = *(const bf16x8*)&Bs[(wc * 64 + ni * 16 + l16) * 32 + quad * 8];
#pragma unroll
    for (int mi = 0; mi < 4; ++mi)
#pragma unroll
      for (int ni = 0; ni < 4; ++ni)
        acc[mi][ni] = __builtin_amdgcn_mfma_f32_16x16x32_bf16(
            af[mi], bfr[ni], acc[mi][ni], 0, 0, 0);
  }

  // Epilogue. C/D layout: col = lane&15, row = quad*4 + reg.
#pragma unroll
  for (int mi = 0; mi < 4; ++mi) {
    const int rbase = m0 + wr * 64 + mi * 16 + quad * 4;
#pragma unroll
    for (int ni = 0; ni < 4; ++ni) {
      const int col = n0 + wc * 64 + ni * 16 + l16;
#pragma unroll
      for (int r = 0; r < 4; ++r) {
        const int row = rbase + r;
        const size_t idx = (size_t)row * N + col;
        const float v = acc[mi][ni][r];
        if (MODE == 0) {
          Cf[idx] = v;
        } else if (MODE == 1) {
          O1[idx] = (bf16)v;
        } else if (MODE == 2) {
          O1[idx] = (bf16)(-v);  // (W3)^T = -W3 (antisymmetric)
          const float w  = (float)Wb[idx];
          const float w2 = (float)W2b[idx];
          const float d  = (row == col) ? 1.0f : 0.0f;
          O2[idx] = (bf16)(C6 * d + C7 * w + C8 * w2 + C9 * v);
        } else if (MODE == 3) {
          const float w  = (float)Wb[idx];
          const float w2 = (float)W2b[idx];
          const float d  = (row == col) ? 1.0f : 0.0f;
          O1[idx] = (bf16)(v + C3 * d + C4 * w + C5 * w2);
        } else {  // MODE 4
          const float w  = (float)Wb[idx];
          const float w2 = (float)W2b[idx];
          const float d  = (row == col) ? 1.0f : 0.0f;
          O1[idx] = (bf16)(v + d + w + 0.5f * w2);
        }
      }
    }
  }
}

extern "C" void kernel_launch(void* const* d_in, const int* in_sizes, int n_in,
                              void* d_out, int out_size, void* d_ws, size_t ws_size,
                              hipStream_t stream) {
  const float* X     = (const float*)d_in[0];
  const float* Sflat = (const float*)d_in[1];
  float* out = (float*)d_out;
  char* ws = (char*)d_ws;

  // Workspace (80 MB total, same footprint as the passing round-0 layout):
  bf16* Xb   = (bf16*)(ws);                 // 32 MB  bf16(X)
  bf16* Wb   = (bf16*)(ws + (32u << 20));   //  8 MB  bf16(W),   W = -S
  bf16* Wtb  = (bf16*)(ws + (40u << 20));   //  8 MB  bf16(W^T); dead after G2 -> Qtb
  bf16* W2b  = (bf16*)(ws + (48u << 20));   //  8 MB  bf16(W^2)
  bf16* W3nb = (bf16*)(ws + (56u << 20));   //  8 MB  bf16(-W^3) = (W^3)^T
  bf16* P2b  = (bf16*)(ws + (64u << 20));   //  8 MB
  bf16* P1b  = (bf16*)(ws + (72u << 20));   //  8 MB
  bf16* Qtb  = Wtb;                         // reuse: bf16(Q^T)

  unfold_kernel<<<(N_DIM * N_DIM) / 256, 256, 0, stream>>>(Sflat, Wb, Wtb);
  cast_kernel<<<(BATCH_SZ * N_DIM / 4) / 256, 256, 0, stream>>>(X, Xb);

  const dim3 gW(N_DIM / 128, N_DIM / 128);
  // G1: W2 = W @ W
  gemm_bt<1><<<gW, 256, 0, stream>>>(Wb, Wtb, nullptr, W2b, nullptr,
                                     nullptr, nullptr, N_DIM, N_DIM, N_DIM);
  // G2: W3 = W2 @ W; emit (W3)^T and P2 = C6 I + C7 W + C8 W2 + C9 W3
  gemm_bt<2><<<gW, 256, 0, stream>>>(W2b, Wtb, nullptr, W3nb, P2b,
                                     Wb, W2b, N_DIM, N_DIM, N_DIM);
  // G3: P1 = C3 I + C4 W + C5 W2 + P2 @ W3
  gemm_bt<3><<<gW, 256, 0, stream>>>(P2b, W3nb, nullptr, P1b, nullptr,
                                     Wb, W2b, N_DIM, N_DIM, N_DIM);
  // G4: Q^T = I + W + 0.5 W2 + P1 @ W3
  gemm_bt<4><<<gW, 256, 0, stream>>>(P1b, W3nb, nullptr, Qtb, nullptr,
                                     Wb, W2b, N_DIM, N_DIM, N_DIM);
  // G5: out = X @ Q   (Bt = Q^T row-major)
  gemm_bt<0><<<dim3(N_DIM / 128, BATCH_SZ / 128), 256, 0, stream>>>(
      Xb, Qtb, out, nullptr, nullptr, nullptr, nullptr,
      BATCH_SZ, N_DIM, N_DIM);
}

// Round 3
// 385.163 us; speedup vs baseline: 1.8213x; 1.0779x over previous
//
#include <hip/hip_runtime.h>
#include <hip/hip_bf16.h>
#include <stdint.h>

#define N_DIM 2048
#define BATCH_SZ 8192

typedef __bf16 bf16;
typedef __bf16 bf16x4 __attribute__((ext_vector_type(4)));
typedef __bf16 bf16x8 __attribute__((ext_vector_type(8)));
typedef float f32x4 __attribute__((ext_vector_type(4)));

// Taylor coefficients 1/i!
#define C3 (1.0f/6.0f)
#define C4 (1.0f/24.0f)
#define C5 (1.0f/120.0f)
#define C6 (1.0f/720.0f)
#define C7 (1.0f/5040.0f)
#define C8 (1.0f/40320.0f)
#define C9 (1.0f/362880.0f)

// Async global->LDS, 16B per lane. LDS dest is wave-uniform base + lane*16.
__device__ __forceinline__ void gld16(const bf16* g, bf16* l) {
  __builtin_amdgcn_global_load_lds(
      (const __attribute__((address_space(1))) void*)g,
      (__attribute__((address_space(3))) void*)l, 16, 0, 0);
}

// Build Wb = bf16(W) where W = -S (so exp(W) = Q^T), Wtb = bf16(W^T) = bf16(S).
__global__ void unfold_kernel(const float* __restrict__ Sflat,
                              bf16* __restrict__ Wb,
                              bf16* __restrict__ Wtb) {
  int idx = blockIdx.x * blockDim.x + threadIdx.x;
  int i = idx >> 11;            // row
  int j = idx & (N_DIM - 1);    // col
  float v = 0.0f;               // v = S[i][j]
  if (i < j) {
    int fi = i * (N_DIM - 1) - ((i * (i - 1)) >> 1) + (j - i - 1);
    v = Sflat[fi];
  } else if (i > j) {
    int fi = j * (N_DIM - 1) - ((j * (j - 1)) >> 1) + (i - j - 1);
    v = -Sflat[fi];
  }
  Wb[idx]  = (bf16)(-v);   // W = -S
  Wtb[idx] = (bf16)(v);    // W^T = S
}

// fp32 -> bf16 elementwise (vectorized x4)
__global__ void cast_kernel(const float* __restrict__ in, bf16* __restrict__ out) {
  int t = blockIdx.x * blockDim.x + threadIdx.x;
  float4 v = ((const float4*)in)[t];
  bf16x4 o;
  o.x = (bf16)v.x; o.y = (bf16)v.y; o.z = (bf16)v.z; o.w = (bf16)v.w;
  ((bf16x4*)out)[t] = o;
}

// C(MxN) = A(MxK) @ Bt(NxK)^T, bf16 in, fp32 accumulate.
// TM x 128 block tile (TM = 128 or 64), BK=32, 4 waves, global_load_lds
// width-16 staging with XOR-swizzled LDS layout (kills ds_read_b128 bank
// conflicts: bank-quad = 4*(l16&1) + (quad ^ ((l16>>1)&3)) covers all 8
// groups with 2 lanes each — 2-way aliasing is free).
// MODE 0: Cf[idx] = acc                                  (final output)
// MODE 1: O1 = bf16(acc)                                 (W2 = W@W)
// MODE 2: O1 = bf16(-acc)  [W3^T],  O2 = bf16(P2)        (W3 = W2@W)
//         P2 = C6*I + C7*W + C8*W2 + C9*W3
// MODE 3: O1 = bf16(acc + C3*I + C4*W + C5*W2)           (P1 = B1 + P2@W3)
// MODE 4: O1 = bf16(acc +    I +    W + 0.5*W2)          (Q^T = B0 + P1@W3)
template <int MODE, int TM>
__global__ __launch_bounds__(256) void gemm_bt(
    const bf16* __restrict__ A, const bf16* __restrict__ Bt,
    float* __restrict__ Cf, bf16* __restrict__ O1, bf16* __restrict__ O2,
    const bf16* __restrict__ Wb, const bf16* __restrict__ W2b,
    int M, int N, int K) {
  constexpr int MI  = TM / 32;    // m-fragments per wave
  constexpr int ACH = TM / 64;    // 64-row staging chunks for A
  __shared__ __align__(16) bf16 As[TM * 32];
  __shared__ __align__(16) bf16 Bs[128 * 32];

  const int tid  = threadIdx.x;
  const int lane = tid & 63;
  const int wave = tid >> 6;
  const int wr   = wave >> 1;
  const int wc   = wave & 1;
  const int quad = lane >> 4;
  const int l16  = lane & 15;
  const int m0 = blockIdx.y * TM;
  const int n0 = blockIdx.x * 128;

  // Staging: wave w stages rows [w*16, w*16+16) of each 64-row chunk.
  // Lane i -> row i>>2 within chunk; global seg XOR-swizzled by (row>>1)&3
  // (= (lane>>3)&3 here), so that LDS[row][slot] = G[row][slot ^ x(row)].
  const int srow = wave * 16 + (lane >> 2);
  const int sseg = (((lane & 3) ^ ((lane >> 3) & 3)) * 8);

  const bf16* gA[ACH];
  bf16* lA[ACH];
#pragma unroll
  for (int c = 0; c < ACH; ++c) {
    gA[c] = A + (size_t)(m0 + c * 64 + srow) * K + sseg;
    lA[c] = As + (c * 64 + wave * 16) * 32;
  }
  const bf16* gB[2];
  bf16* lB[2];
#pragma unroll
  for (int c = 0; c < 2; ++c) {
    gB[c] = Bt + (size_t)(n0 + c * 64 + srow) * K + sseg;
    lB[c] = Bs + (c * 64 + wave * 16) * 32;
  }

  f32x4 acc[MI][4] = {};
  const int xsw = (l16 >> 1) & 3;   // reader-side swizzle index

  for (int k0 = 0; k0 < K; k0 += 32) {
    __syncthreads();                       // previous consumers done with LDS
#pragma unroll
    for (int c = 0; c < ACH; ++c) { gld16(gA[c], lA[c]); gA[c] += 32; }
#pragma unroll
    for (int c = 0; c < 2;   ++c) { gld16(gB[c], lB[c]); gB[c] += 32; }
    __syncthreads();                       // drains vmcnt -> LDS valid

    bf16x8 af[MI], bfr[4];
#pragma unroll
    for (int mi = 0; mi < MI; ++mi)
      af[mi] = *(const bf16x8*)&As[(wr * (TM / 2) + mi * 16 + l16) * 32 +
                                   ((quad ^ xsw) * 8)];
#pragma unroll
    for (int ni = 0; ni < 4; ++ni)
      bfr[ni] = *(const bf16x8*)&Bs[(wc * 64 + ni * 16 + l16) * 32 +
                                    ((quad ^ xsw) * 8)];
#pragma unroll
    for (int mi = 0; mi < MI; ++mi)
#pragma unroll
      for (int ni = 0; ni < 4; ++ni)
        acc[mi][ni] = __builtin_amdgcn_mfma_f32_16x16x32_bf16(
            af[mi], bfr[ni], acc[mi][ni], 0, 0, 0);
  }

  // Epilogue. C/D layout: col = lane&15, row = quad*4 + reg.
#pragma unroll
  for (int mi = 0; mi < MI; ++mi) {
    const int rbase = m0 + wr * (TM / 2) + mi * 16 + quad * 4;
#pragma unroll
    for (int ni = 0; ni < 4; ++ni) {
      const int col = n0 + wc * 64 + ni * 16 + l16;
#pragma unroll
      for (int r = 0; r < 4; ++r) {
        const int row = rbase + r;
        const size_t idx = (size_t)row * N + col;
        const float v = acc[mi][ni][r];
        if (MODE == 0) {
          Cf[idx] = v;
        } else if (MODE == 1) {
          O1[idx] = (bf16)v;
        } else if (MODE == 2) {
          O1[idx] = (bf16)(-v);  // (W3)^T = -W3 (antisymmetric)
          const float w  = (float)Wb[idx];
          const float w2 = (float)W2b[idx];
          const float d  = (row == col) ? 1.0f : 0.0f;
          O2[idx] = (bf16)(C6 * d + C7 * w + C8 * w2 + C9 * v);
        } else if (MODE == 3) {
          const float w  = (float)Wb[idx];
          const float w2 = (float)W2b[idx];
          const float d  = (row == col) ? 1.0f : 0.0f;
          O1[idx] = (bf16)(v + C3 * d + C4 * w + C5 * w2);
        } else {  // MODE 4
          const float w  = (float)Wb[idx];
          const float w2 = (float)W2b[idx];
          const float d  = (row == col) ? 1.0f : 0.0f;
          O1[idx] = (bf16)(v + d + w + 0.5f * w2);
        }
      }
    }
  }
}

extern "C" void kernel_launch(void* const* d_in, const int* in_sizes, int n_in,
                              void* d_out, int out_size, void* d_ws, size_t ws_size,
                              hipStream_t stream) {
  const float* X     = (const float*)d_in[0];
  const float* Sflat = (const float*)d_in[1];
  float* out = (float*)d_out;
  char* ws = (char*)d_ws;

  // Workspace (80 MB total):
  bf16* Xb   = (bf16*)(ws);                 // 32 MB  bf16(X)
  bf16* Wb   = (bf16*)(ws + (32u << 20));   //  8 MB  bf16(W),   W = -S
  bf16* Wtb  = (bf16*)(ws + (40u << 20));   //  8 MB  bf16(W^T); dead after G2 -> Qtb
  bf16* W2b  = (bf16*)(ws + (48u << 20));   //  8 MB  bf16(W^2)
  bf16* W3nb = (bf16*)(ws + (56u << 20));   //  8 MB  bf16(-W^3) = (W^3)^T
  bf16* P2b  = (bf16*)(ws + (64u << 20));   //  8 MB
  bf16* P1b  = (bf16*)(ws + (72u << 20));   //  8 MB
  bf16* Qtb  = Wtb;                         // reuse: bf16(Q^T)

  unfold_kernel<<<(N_DIM * N_DIM) / 256, 256, 0, stream>>>(Sflat, Wb, Wtb);
  cast_kernel<<<(BATCH_SZ * N_DIM / 4) / 256, 256, 0, stream>>>(X, Xb);

  // Weight GEMMs: 64x128 tiles -> 512 blocks = 2 blocks/CU (latency hiding).
  const dim3 gW(N_DIM / 128, N_DIM / 64);
  // G1: W2 = W @ W
  gemm_bt<1, 64><<<gW, 256, 0, stream>>>(Wb, Wtb, nullptr, W2b, nullptr,
                                         nullptr, nullptr, N_DIM, N_DIM, N_DIM);
  // G2: W3 = W2 @ W; emit (W3)^T and P2 = C6 I + C7 W + C8 W2 + C9 W3
  gemm_bt<2, 64><<<gW, 256, 0, stream>>>(W2b, Wtb, nullptr, W3nb, P2b,
                                         Wb, W2b, N_DIM, N_DIM, N_DIM);
  // G3: P1 = C3 I + C4 W + C5 W2 + P2 @ W3
  gemm_bt<3, 64><<<gW, 256, 0, stream>>>(P2b, W3nb, nullptr, P1b, nullptr,
                                         Wb, W2b, N_DIM, N_DIM, N_DIM);
  // G4: Q^T = I + W + 0.5 W2 + P1 @ W3
  gemm_bt<4, 64><<<gW, 256, 0, stream>>>(P1b, W3nb, nullptr, Qtb, nullptr,
                                         Wb, W2b, N_DIM, N_DIM, N_DIM);
  // G5: out = X @ Q   (Bt = Q^T row-major), 128x128 tiles -> 1024 blocks.
  gemm_bt<0, 128><<<dim3(N_DIM / 128, BATCH_SZ / 128), 256, 0, stream>>>(
      Xb, Qtb, out, nullptr, nullptr, nullptr, nullptr,
      BATCH_SZ, N_DIM, N_DIM);
}

// Round 4
// 306.138 us; speedup vs baseline: 2.2915x; 1.2581x over previous
//
#include <hip/hip_runtime.h>
#include <hip/hip_bf16.h>
#include <stdint.h>

#define N_DIM 2048
#define BATCH_SZ 8192

typedef __bf16 bf16;
typedef __bf16 bf16x4 __attribute__((ext_vector_type(4)));
typedef __bf16 bf16x8 __attribute__((ext_vector_type(8)));
typedef float f32x4 __attribute__((ext_vector_type(4)));

// Async global->LDS, 16B per lane. LDS dest is wave-uniform base + lane*16.
__device__ __forceinline__ void gld16(const bf16* g, bf16* l) {
  __builtin_amdgcn_global_load_lds(
      (const __attribute__((address_space(1))) void*)g,
      (__attribute__((address_space(3))) void*)l, 16, 0, 0);
}

// Build Wb = bf16(W) where W = -S (so exp(W) = Q^T), Wtb = bf16(W^T) = bf16(S).
__global__ void unfold_kernel(const float* __restrict__ Sflat,
                              bf16* __restrict__ Wb,
                              bf16* __restrict__ Wtb) {
  int idx = blockIdx.x * blockDim.x + threadIdx.x;
  int i = idx >> 11;            // row
  int j = idx & (N_DIM - 1);    // col
  float v = 0.0f;               // v = S[i][j]
  if (i < j) {
    int fi = i * (N_DIM - 1) - ((i * (i - 1)) >> 1) + (j - i - 1);
    v = Sflat[fi];
  } else if (i > j) {
    int fi = j * (N_DIM - 1) - ((j * (j - 1)) >> 1) + (i - j - 1);
    v = -Sflat[fi];
  }
  Wb[idx]  = (bf16)(-v);   // W = -S
  Wtb[idx] = (bf16)(v);    // W^T = S
}

// fp32 -> bf16 elementwise (vectorized x4)
__global__ void cast_kernel(const float* __restrict__ in, bf16* __restrict__ out) {
  int t = blockIdx.x * blockDim.x + threadIdx.x;
  float4 v = ((const float4*)in)[t];
  bf16x4 o;
  o.x = (bf16)v.x; o.y = (bf16)v.y; o.z = (bf16)v.z; o.w = (bf16)v.w;
  ((bf16x4*)out)[t] = o;
}

// C(MxN) = A(MxK) @ Bt(NxK)^T, bf16 in, fp32 accumulate.
// TM x 128 block tile (TM = 128 or 64), BK=32, 4 waves, global_load_lds
// width-16 staging with XOR-swizzled LDS layout (conflict-free, verified R3:
// SQ_LDS_BANK_CONFLICT = 0).
// Degree-4 Paterson-Stockmeyer: exp(W) = I + W + W2*(I/2 + W/6 + W2/24).
// MODE 0: Cf[idx] = acc                                   (final out = X@Q)
// MODE 1: O1 = bf16(acc) [W2];  O2 = bf16(I/2 - W/6 + acc/24) [B^T operand]
// MODE 2: O1 = bf16(acc + I + W)                          (Q^T)
template <int MODE, int TM>
__global__ __launch_bounds__(256) void gemm_bt(
    const bf16* __restrict__ A, const bf16* __restrict__ Bt,
    float* __restrict__ Cf, bf16* __restrict__ O1, bf16* __restrict__ O2,
    const bf16* __restrict__ Wb,
    int M, int N, int K) {
  constexpr int MI  = TM / 32;    // m-fragments per wave
  constexpr int ACH = TM / 64;    // 64-row staging chunks for A
  __shared__ __align__(16) bf16 As[TM * 32];
  __shared__ __align__(16) bf16 Bs[128 * 32];

  const int tid  = threadIdx.x;
  const int lane = tid & 63;
  const int wave = tid >> 6;
  const int wr   = wave >> 1;
  const int wc   = wave & 1;
  const int quad = lane >> 4;
  const int l16  = lane & 15;
  const int m0 = blockIdx.y * TM;
  const int n0 = blockIdx.x * 128;

  // Staging: wave w stages rows [w*16, w*16+16) of each 64-row chunk.
  // Lane i -> row i>>2 within chunk; global seg XOR-swizzled by (row>>1)&3
  // so LDS[row][slot] = G[row][slot ^ x(row)] -> conflict-free reads.
  const int srow = wave * 16 + (lane >> 2);
  const int sseg = (((lane & 3) ^ ((lane >> 3) & 3)) * 8);

  const bf16* gA[ACH];
  bf16* lA[ACH];
#pragma unroll
  for (int c = 0; c < ACH; ++c) {
    gA[c] = A + (size_t)(m0 + c * 64 + srow) * K + sseg;
    lA[c] = As + (c * 64 + wave * 16) * 32;
  }
  const bf16* gB[2];
  bf16* lB[2];
#pragma unroll
  for (int c = 0; c < 2; ++c) {
    gB[c] = Bt + (size_t)(n0 + c * 64 + srow) * K + sseg;
    lB[c] = Bs + (c * 64 + wave * 16) * 32;
  }

  f32x4 acc[MI][4] = {};
  const int xsw = (l16 >> 1) & 3;   // reader-side swizzle index

  for (int k0 = 0; k0 < K; k0 += 32) {
    __syncthreads();                       // previous consumers done with LDS
#pragma unroll
    for (int c = 0; c < ACH; ++c) { gld16(gA[c], lA[c]); gA[c] += 32; }
#pragma unroll
    for (int c = 0; c < 2;   ++c) { gld16(gB[c], lB[c]); gB[c] += 32; }
    __syncthreads();                       // drains vmcnt -> LDS valid

    bf16x8 af[MI], bfr[4];
#pragma unroll
    for (int mi = 0; mi < MI; ++mi)
      af[mi] = *(const bf16x8*)&As[(wr * (TM / 2) + mi * 16 + l16) * 32 +
                                   ((quad ^ xsw) * 8)];
#pragma unroll
    for (int ni = 0; ni < 4; ++ni)
      bfr[ni] = *(const bf16x8*)&Bs[(wc * 64 + ni * 16 + l16) * 32 +
                                    ((quad ^ xsw) * 8)];
#pragma unroll
    for (int mi = 0; mi < MI; ++mi)
#pragma unroll
      for (int ni = 0; ni < 4; ++ni)
        acc[mi][ni] = __builtin_amdgcn_mfma_f32_16x16x32_bf16(
            af[mi], bfr[ni], acc[mi][ni], 0, 0, 0);
  }

  // Epilogue. C/D layout: col = lane&15, row = quad*4 + reg.
#pragma unroll
  for (int mi = 0; mi < MI; ++mi) {
    const int rbase = m0 + wr * (TM / 2) + mi * 16 + quad * 4;
#pragma unroll
    for (int ni = 0; ni < 4; ++ni) {
      const int col = n0 + wc * 64 + ni * 16 + l16;
#pragma unroll
      for (int r = 0; r < 4; ++r) {
        const int row = rbase + r;
        const size_t idx = (size_t)row * N + col;
        const float v = acc[mi][ni][r];
        if (MODE == 0) {
          Cf[idx] = v;
        } else if (MODE == 1) {
          // v = W2[row][col]. Emit W2 and the Bt operand for G2:
          // B = I/2 + W/6 + W2/24  ->  B^T = I/2 - W/6 + W2/24 (W2 symmetric).
          O1[idx] = (bf16)v;
          const float w = (float)Wb[idx];
          const float d = (row == col) ? 1.0f : 0.0f;
          O2[idx] = (bf16)(0.5f * d - (1.0f / 6.0f) * w + (1.0f / 24.0f) * v);
        } else {  // MODE 2: Q^T = acc + I + W
          const float w = (float)Wb[idx];
          const float d = (row == col) ? 1.0f : 0.0f;
          O1[idx] = (bf16)(v + d + w);
        }
      }
    }
  }
}

extern "C" void kernel_launch(void* const* d_in, const int* in_sizes, int n_in,
                              void* d_out, int out_size, void* d_ws, size_t ws_size,
                              hipStream_t stream) {
  const float* X     = (const float*)d_in[0];
  const float* Sflat = (const float*)d_in[1];
  float* out = (float*)d_out;
  char* ws = (char*)d_ws;

  // Workspace (72 MB total):
  bf16* Xb   = (bf16*)(ws);                 // 32 MB  bf16(X)
  bf16* Wb   = (bf16*)(ws + (32u << 20));   //  8 MB  bf16(W),   W = -S
  bf16* Wtb  = (bf16*)(ws + (40u << 20));   //  8 MB  bf16(W^T)
  bf16* W2b  = (bf16*)(ws + (48u << 20));   //  8 MB  bf16(W^2)
  bf16* Btm  = (bf16*)(ws + (56u << 20));   //  8 MB  bf16(B^T) operand for G2
  bf16* Qtb  = (bf16*)(ws + (64u << 20));   //  8 MB  bf16(Q^T)

  unfold_kernel<<<(N_DIM * N_DIM) / 256, 256, 0, stream>>>(Sflat, Wb, Wtb);
  cast_kernel<<<(BATCH_SZ * N_DIM / 4) / 256, 256, 0, stream>>>(X, Xb);

  // Weight GEMMs: 64x128 tiles -> 512 blocks = 2 blocks/CU.
  const dim3 gW(N_DIM / 128, N_DIM / 64);
  // G1: W2 = W @ W;  epilogue also emits B^T = I/2 - W/6 + W2/24.
  gemm_bt<1, 64><<<gW, 256, 0, stream>>>(Wb, Wtb, nullptr, W2b, Btm,
                                         Wb, N_DIM, N_DIM, N_DIM);
  // G2: Q^T = I + W + W2 @ B   (Bt operand = B^T).
  gemm_bt<2, 64><<<gW, 256, 0, stream>>>(W2b, Btm, nullptr, Qtb, nullptr,
                                         Wb, N_DIM, N_DIM, N_DIM);
  // G3: out = X @ Q   (Bt = Q^T row-major), 128x128 tiles -> 1024 blocks.
  gemm_bt<0, 128><<<dim3(N_DIM / 128, BATCH_SZ / 128), 256, 0, stream>>>(
      Xb, Qtb, out, nullptr, nullptr, nullptr,
      BATCH_SZ, N_DIM, N_DIM);
}